// Round 1
// baseline (2599.042 us; speedup 1.0000x reference)
//
#include <hip/hip_runtime.h>
#include <hip/hip_bf16.h>

#define D 128
#define TWO_D 256

// wr[r*256 + m] = dot(W[m, :], rel[r, :])   (m in [0,256), row-major W [256][128])
__global__ __launch_bounds__(256) void compute_wr(const float* __restrict__ W,
                                                  const float* __restrict__ rel,
                                                  float* __restrict__ wr) {
    int r = blockIdx.x;
    int m = threadIdx.x;
    const float4* wrow = (const float4*)(W + (size_t)m * D);
    const float4* rrow = (const float4*)(rel + (size_t)r * D);
    float s = 0.f;
#pragma unroll
    for (int k = 0; k < D / 4; ++k) {
        float4 a = wrow[k];
        float4 b = rrow[k];
        s += a.x * b.x + a.y * b.y + a.z * b.z + a.w * b.w;
    }
    wr[r * TWO_D + m] = s;
}

// One wavefront per edge: e_exp[j] = exp(leakyrelu(h_u . wr_h + t_e . wr_t))
// plus atomic accumulation of softmax denominators by head and by tail.
__global__ __launch_bounds__(256) void edge_logits(const float* __restrict__ usr,
                                                   const float* __restrict__ ent,
                                                   const float* __restrict__ wr,
                                                   const int* __restrict__ head,
                                                   const int* __restrict__ tail,
                                                   const int* __restrict__ etype,
                                                   float* __restrict__ e_exp,
                                                   float* __restrict__ denom_u,
                                                   float* __restrict__ denom_i,
                                                   int E) {
    int wid = (int)((blockIdx.x * (size_t)blockDim.x + threadIdx.x) >> 6);
    int lane = threadIdx.x & 63;
    if (wid >= E) return;
    int h = head[wid];
    int t = tail[wid];
    int r = etype[wid];
    const float2* hu = (const float2*)(usr + (size_t)h * D);
    const float2* te = (const float2*)(ent + (size_t)t * D);
    const float2* wh = (const float2*)(wr + (size_t)r * TWO_D);
    const float2* wt = (const float2*)(wr + (size_t)r * TWO_D + D);
    float2 a = hu[lane];
    float2 b = wh[lane];
    float s = a.x * b.x + a.y * b.y;
    float2 c = te[lane];
    float2 d = wt[lane];
    s += c.x * d.x + c.y * d.y;
#pragma unroll
    for (int off = 32; off; off >>= 1) s += __shfl_xor(s, off, 64);
    if (lane == 0) {
        float e = s > 0.f ? s : 0.2f * s;   // LeakyReLU(0.2)
        float ex = expf(e);
        e_exp[wid] = ex;
        unsafeAtomicAdd(denom_u + h, ex);
        unsafeAtomicAdd(denom_i + t, ex);
    }
}

// One wavefront per edge: acc_u[head] += t_e * (e_exp/denom_u[head]);
//                         acc_i[tail] += h_u * (e_exp/denom_i[tail]);
__global__ __launch_bounds__(256) void edge_aggregate(const float* __restrict__ usr,
                                                      const float* __restrict__ ent,
                                                      const float* __restrict__ e_exp,
                                                      const float* __restrict__ denom_u,
                                                      const float* __restrict__ denom_i,
                                                      const int* __restrict__ head,
                                                      const int* __restrict__ tail,
                                                      float* __restrict__ acc_u,
                                                      float* __restrict__ acc_i,
                                                      int E) {
    int wid = (int)((blockIdx.x * (size_t)blockDim.x + threadIdx.x) >> 6);
    int lane = threadIdx.x & 63;
    if (wid >= E) return;
    int h = head[wid];
    int t = tail[wid];
    float ex = e_exp[wid];
    float wu = ex / denom_u[h];
    float wi = ex / denom_i[t];
    const float2* hu = (const float2*)(usr + (size_t)h * D);
    const float2* te = (const float2*)(ent + (size_t)t * D);
    float2 a = te[lane];
    float* au = acc_u + (size_t)h * D + 2 * lane;
    unsafeAtomicAdd(au, a.x * wu);
    unsafeAtomicAdd(au + 1, a.y * wu);
    float2 b = hu[lane];
    float* ai = acc_i + (size_t)t * D + 2 * lane;
    unsafeAtomicAdd(ai, b.x * wi);
    unsafeAtomicAdd(ai + 1, b.y * wi);
}

// One wavefront per row: dst[row] += acc[row] / max(||acc[row]||, 1e-8)
__global__ __launch_bounds__(256) void finalize_rows(float* __restrict__ dst,
                                                     const float* __restrict__ acc,
                                                     int N) {
    int row = (int)((blockIdx.x * (size_t)blockDim.x + threadIdx.x) >> 6);
    int lane = threadIdx.x & 63;
    if (row >= N) return;
    const float2* a = (const float2*)(acc + (size_t)row * D);
    float2 v = a[lane];
    float s = v.x * v.x + v.y * v.y;
#pragma unroll
    for (int off = 32; off; off >>= 1) s += __shfl_xor(s, off, 64);
    float inv = 1.f / fmaxf(sqrtf(s), 1e-8f);
    float2* d = (float2*)(dst + (size_t)row * D);
    float2 o = d[lane];
    o.x += v.x * inv;
    o.y += v.y * inv;
    d[lane] = o;
}

extern "C" void kernel_launch(void* const* d_in, const int* in_sizes, int n_in,
                              void* d_out, int out_size, void* d_ws, size_t ws_size,
                              hipStream_t stream) {
    const float* user = (const float*)d_in[0];
    const float* rel  = (const float*)d_in[1];
    const float* ent  = (const float*)d_in[2];
    const float* W    = (const float*)d_in[3];
    const int* eidx   = (const int*)d_in[4];
    const int* etype  = (const int*)d_in[5];

    int Nu = in_sizes[0] / D;
    int R  = in_sizes[1] / D;
    int Ne = in_sizes[2] / D;
    int E  = in_sizes[5];
    const int* head = eidx;
    const int* tail = eidx + E;

    float* out_usr = (float*)d_out;
    float* out_ent = out_usr + (size_t)Nu * D;

    float* p = (float*)d_ws;
    float* acc_u = p;   p += (size_t)Nu * D;
    float* acc_i = p;   p += (size_t)Ne * D;
    float* e_exp = p;   p += E;
    float* denom_u = p; p += Nu;
    float* denom_i = p; p += Ne;   // contiguous with denom_u
    float* wr = p;      p += (size_t)R * TWO_D;

    size_t usr_bytes = (size_t)Nu * D * sizeof(float);
    size_t ent_bytes = (size_t)Ne * D * sizeof(float);

    // Initialize the evolving state in d_out.
    hipMemcpyAsync(out_usr, user, usr_bytes, hipMemcpyDeviceToDevice, stream);
    hipMemcpyAsync(out_ent, ent, ent_bytes, hipMemcpyDeviceToDevice, stream);
    compute_wr<<<R, 256, 0, stream>>>(W, rel, wr);

    int edge_blocks = (E + 3) / 4;  // 4 waves (edges) per 256-thread block

    for (int hop = 0; hop < 2; ++hop) {
        // acc = current state (so segsum + x is built in); denominators = 0
        hipMemcpyAsync(acc_u, out_usr, usr_bytes, hipMemcpyDeviceToDevice, stream);
        hipMemcpyAsync(acc_i, out_ent, ent_bytes, hipMemcpyDeviceToDevice, stream);
        hipMemsetAsync(denom_u, 0, (size_t)(Nu + Ne) * sizeof(float), stream);

        edge_logits<<<edge_blocks, 256, 0, stream>>>(out_usr, out_ent, wr, head, tail,
                                                     etype, e_exp, denom_u, denom_i, E);
        edge_aggregate<<<edge_blocks, 256, 0, stream>>>(out_usr, out_ent, e_exp,
                                                        denom_u, denom_i, head, tail,
                                                        acc_u, acc_i, E);
        finalize_rows<<<(Nu + 3) / 4, 256, 0, stream>>>(out_usr, acc_u, Nu);
        finalize_rows<<<(Ne + 3) / 4, 256, 0, stream>>>(out_ent, acc_i, Ne);
    }
}

// Round 3
// 1334.244 us; speedup vs baseline: 1.9480x; 1.9480x over previous
//
#include <hip/hip_runtime.h>
#include <hip/hip_bf16.h>

#define D 128
#define TWO_D 256

// wr[r*256 + m] = dot(W[m, :], rel[r, :])   (m in [0,256), row-major W [256][128])
__global__ __launch_bounds__(256) void compute_wr(const float* __restrict__ W,
                                                  const float* __restrict__ rel,
                                                  float* __restrict__ wr) {
    int r = blockIdx.x;
    int m = threadIdx.x;
    const float4* wrow = (const float4*)(W + (size_t)m * D);
    const float4* rrow = (const float4*)(rel + (size_t)r * D);
    float s = 0.f;
#pragma unroll
    for (int k = 0; k < D / 4; ++k) {
        float4 a = wrow[k];
        float4 b = rrow[k];
        s += a.x * b.x + a.y * b.y + a.z * b.z + a.w * b.w;
    }
    wr[r * TWO_D + m] = s;
}

// Degree count: deg_u[head[e]]++, deg_i[tail[e]]++
__global__ __launch_bounds__(256) void count_deg(const int* __restrict__ head,
                                                 const int* __restrict__ tail,
                                                 int* __restrict__ deg_u,
                                                 int* __restrict__ deg_i, int E) {
    int e = blockIdx.x * 256 + threadIdx.x;
    if (e >= E) return;
    atomicAdd(deg_u + head[e], 1);
    atomicAdd(deg_i + tail[e], 1);
}

// Single-block exclusive scan over N<=100352 elements (1024 threads, chunked).
__global__ __launch_bounds__(1024) void exscan100k(const int* __restrict__ deg,
                                                   int* __restrict__ rowptr, int N) {
    __shared__ int lds[1024];
    int tid = threadIdx.x;
    int chunk = (N + 1023) >> 10;
    int start = tid * chunk;
    int end = min(start + chunk, N);
    int s = 0;
    for (int i = start; i < end; ++i) s += deg[i];
    lds[tid] = s;
    __syncthreads();
    for (int off = 1; off < 1024; off <<= 1) {
        int t = (tid >= off) ? lds[tid - off] : 0;
        __syncthreads();
        lds[tid] += t;
        __syncthreads();
    }
    int run = lds[tid] - s;  // exclusive prefix of this thread's chunk
    for (int i = start; i < end; ++i) { rowptr[i] = run; run += deg[i]; }
    if (tid == 1023) rowptr[N] = lds[1023];
}

// Scatter edge ids into CSR edge lists using cursor fetch-add.
__global__ __launch_bounds__(256) void fill_elist(const int* __restrict__ head,
                                                  const int* __restrict__ tail,
                                                  int* __restrict__ cur_u,
                                                  int* __restrict__ cur_i,
                                                  int* __restrict__ elist_u,
                                                  int* __restrict__ elist_i, int E) {
    int e = blockIdx.x * 256 + threadIdx.x;
    if (e >= E) return;
    int su = atomicAdd(cur_u + head[e], 1);
    elist_u[su] = e;
    int si = atomicAdd(cur_i + tail[e], 1);
    elist_i[si] = e;
}

// One wavefront per edge: e_exp[j] = exp(leakyrelu(h_u . wr_h + t_e . wr_t))
__global__ __launch_bounds__(256) void edge_logits(const float* __restrict__ usr,
                                                   const float* __restrict__ ent,
                                                   const float* __restrict__ wr,
                                                   const int* __restrict__ head,
                                                   const int* __restrict__ tail,
                                                   const int* __restrict__ etype,
                                                   float* __restrict__ e_exp, int E) {
    int wid = (int)((blockIdx.x * (size_t)blockDim.x + threadIdx.x) >> 6);
    int lane = threadIdx.x & 63;
    if (wid >= E) return;
    int h = head[wid];
    int t = tail[wid];
    int r = etype[wid];
    const float2* hu = (const float2*)(usr + (size_t)h * D);
    const float2* te = (const float2*)(ent + (size_t)t * D);
    const float2* wh = (const float2*)(wr + (size_t)r * TWO_D);
    const float2* wt = (const float2*)(wr + (size_t)r * TWO_D + D);
    float2 a = hu[lane];
    float2 b = wh[lane];
    float s = a.x * b.x + a.y * b.y;
    float2 c = te[lane];
    float2 d = wt[lane];
    s += c.x * d.x + c.y * d.y;
#pragma unroll
    for (int off = 32; off; off >>= 1) s += __shfl_xor(s, off, 64);
    if (lane == 0) {
        float e = s > 0.f ? s : 0.2f * s;  // LeakyReLU(0.2)
        e_exp[wid] = expf(e);
    }
}

// One wavefront per destination node:
//   acc = sum_j e_j * src_rows[other[j]];  esum = sum_j e_j
//   agg = acc/esum + self;  out = self + agg/max(||agg||,1e-8)
__global__ __launch_bounds__(256) void agg_nodes(const float* __restrict__ src_rows,
                                                 const float* __restrict__ self_rows,
                                                 const float* __restrict__ e_exp,
                                                 const int* __restrict__ rowptr,
                                                 const int* __restrict__ elist,
                                                 const int* __restrict__ other_idx,
                                                 float* __restrict__ dst, int N) {
    int node = (int)((blockIdx.x * (size_t)blockDim.x + threadIdx.x) >> 6);
    int lane = threadIdx.x & 63;
    if (node >= N) return;
    int beg = rowptr[node];
    int end = rowptr[node + 1];
    float ax = 0.f, ay = 0.f, esum = 0.f;
    for (int p = beg; p < end; ++p) {
        int e = elist[p];
        float w = e_exp[e];
        int src = other_idx[e];
        float2 v = ((const float2*)(src_rows + (size_t)src * D))[lane];
        ax += w * v.x;
        ay += w * v.y;
        esum += w;
    }
    float inv_e = (end > beg) ? 1.f / esum : 0.f;
    float2 self = ((const float2*)(self_rows + (size_t)node * D))[lane];
    float gx = ax * inv_e + self.x;
    float gy = ay * inv_e + self.y;
    float n2 = gx * gx + gy * gy;
#pragma unroll
    for (int off = 32; off; off >>= 1) n2 += __shfl_xor(n2, off, 64);
    float inv = 1.f / fmaxf(sqrtf(n2), 1e-8f);
    float2 o;
    o.x = self.x + gx * inv;
    o.y = self.y + gy * inv;
    ((float2*)(dst + (size_t)node * D))[lane] = o;
}

extern "C" void kernel_launch(void* const* d_in, const int* in_sizes, int n_in,
                              void* d_out, int out_size, void* d_ws, size_t ws_size,
                              hipStream_t stream) {
    const float* user = (const float*)d_in[0];
    const float* rel  = (const float*)d_in[1];
    const float* ent  = (const float*)d_in[2];
    const float* W    = (const float*)d_in[3];
    const int* eidx   = (const int*)d_in[4];
    const int* etype  = (const int*)d_in[5];

    int Nu = in_sizes[0] / D;
    int R  = in_sizes[1] / D;
    int Ne = in_sizes[2] / D;
    int E  = in_sizes[5];
    const int* head = eidx;
    const int* tail = eidx + E;

    float* out_usr = (float*)d_out;
    float* out_ent = out_usr + (size_t)Nu * D;

    // Workspace layout
    float* fp = (float*)d_ws;
    float* usr_ws = fp; fp += (size_t)Nu * D;
    float* ent_ws = fp; fp += (size_t)Ne * D;
    float* e_exp  = fp; fp += E;
    float* wr     = fp; fp += (size_t)R * TWO_D;
    int* ip = (int*)fp;
    int* rowptr_u = ip; ip += Nu + 1;
    int* rowptr_i = ip; ip += Ne + 1;
    int* cur_u    = ip; ip += Nu;      // also used as degree array
    int* cur_i    = ip; ip += Ne;      // contiguous with cur_u
    int* elist_u  = ip; ip += E;
    int* elist_i  = ip; ip += E;

    // ---- Build CSR (once; graph is static across hops) ----
    hipMemsetAsync(cur_u, 0, (size_t)(Nu + Ne) * sizeof(int), stream);
    compute_wr<<<R, 256, 0, stream>>>(W, rel, wr);
    count_deg<<<(E + 255) / 256, 256, 0, stream>>>(head, tail, cur_u, cur_i, E);
    exscan100k<<<1, 1024, 0, stream>>>(cur_u, rowptr_u, Nu);
    exscan100k<<<1, 1024, 0, stream>>>(cur_i, rowptr_i, Ne);
    hipMemcpyAsync(cur_u, rowptr_u, (size_t)Nu * sizeof(int), hipMemcpyDeviceToDevice, stream);
    hipMemcpyAsync(cur_i, rowptr_i, (size_t)Ne * sizeof(int), hipMemcpyDeviceToDevice, stream);
    fill_elist<<<(E + 255) / 256, 256, 0, stream>>>(head, tail, cur_u, cur_i,
                                                    elist_u, elist_i, E);

    int edge_blocks = (E + 3) / 4;  // 4 waves per 256-thread block

    // ---- Hop 0: inputs -> ws ----
    edge_logits<<<edge_blocks, 256, 0, stream>>>(user, ent, wr, head, tail, etype, e_exp, E);
    agg_nodes<<<(Nu + 3) / 4, 256, 0, stream>>>(ent, user, e_exp, rowptr_u, elist_u,
                                                tail, usr_ws, Nu);
    agg_nodes<<<(Ne + 3) / 4, 256, 0, stream>>>(user, ent, e_exp, rowptr_i, elist_i,
                                                head, ent_ws, Ne);

    // ---- Hop 1: ws -> d_out ----
    edge_logits<<<edge_blocks, 256, 0, stream>>>(usr_ws, ent_ws, wr, head, tail, etype, e_exp, E);
    agg_nodes<<<(Nu + 3) / 4, 256, 0, stream>>>(ent_ws, usr_ws, e_exp, rowptr_u, elist_u,
                                                tail, out_usr, Nu);
    agg_nodes<<<(Ne + 3) / 4, 256, 0, stream>>>(usr_ws, ent_ws, e_exp, rowptr_i, elist_i,
                                                head, out_ent, Ne);
}